// Round 13
// baseline (146.358 us; speedup 1.0000x reference)
//
#include <hip/hip_runtime.h>
#include <stdint.h>

#define BATCH 4
#define NATOM 1024
#define NTOK  256
#define NBLK  256

typedef unsigned short u16x8 __attribute__((ext_vector_type(8)));
typedef unsigned long long u64;

// ---------------- ws layout (bytes) ----------------
// adj:   [0, 32768)         u64[1024][4]     raw token adjacency bits
// dist:  [32768, 557056)    u16[4][256][256] token APSP (0xFFFF unreachable)
// tok:   [557056, 573440)   int32[4096]
// g:     [573440, 577536)   u8[4096]
// L:     [577536, 579584)   u16[1024]
// f1:    [579584, 580608)   u32[256] barrier-1 flags   (poison 0xAA.. != 1)
// rel1:  [580608, 580612)   u32      barrier-1 release
// f2:    [580672, 581696)   u32[256] barrier-2 flags
// rel2:  [581696, 581700)   u32      barrier-2 release
#define OFF_ADJ  0
#define OFF_DIST 32768
#define OFF_TOK  557056
#define OFF_G    573440
#define OFF_L    577536
#define OFF_F1   579584
#define OFF_REL1 580608
#define OFF_F2   580672
#define OFF_REL2 581696

// Grid-wide barrier immune to ws initial contents: blocks WRITE 1 into their
// own flag slot (any prior value != 1, incl. 0xAAAAAAAA poison or 0); block 0's
// threads poll flags via device-scope RMW reads, then block 0 publishes a
// release word. Requires all blocks co-resident: grid=256 blocks on 256 CUs
// (40KB LDS, 1+ block/CU) guarantees this. Device-scope atomics + threadfence
// per cross-XCD coherence rules.
__device__ __forceinline__ void flag_barrier(unsigned* flags, unsigned* release) {
    __syncthreads();
    __threadfence();
    int t = threadIdx.x;
    if (blockIdx.x == 0) {
        if (t > 0 && t < NBLK) {
            while (atomicAdd(&flags[t], 0u) != 1u) __builtin_amdgcn_s_sleep(2);
        }
        __syncthreads();
        __threadfence();
        if (t == 0) atomicExch(release, 1u);
    } else {
        if (t == 0) {
            atomicExch(&flags[blockIdx.x], 1u);
            while (atomicAdd(release, 0u) != 1u) __builtin_amdgcn_s_sleep(8);
        }
    }
    __syncthreads();
    __threadfence();
}

__global__ __launch_bounds__(256) void k_fused(const int* __restrict__ mono,
                                               const float* __restrict__ a2t,
                                               const float* __restrict__ bonds,
                                               char* __restrict__ ws,
                                               int* __restrict__ out) {
    u64* adjw            = (u64*)(ws + OFF_ADJ);
    unsigned short* distg = (unsigned short*)(ws + OFF_DIST);
    int* tok             = (int*)(ws + OFF_TOK);
    unsigned char* g     = (unsigned char*)(ws + OFF_G);
    unsigned short* Lws  = (unsigned short*)(ws + OFF_L);

    __shared__ u64 adjm[NTOK * 4];               // 8 KB   (phase B)
    __shared__ unsigned usable32[8];
    __shared__ unsigned short dist[64 * NTOK];   // 32 KB  (phase B)

    int t    = threadIdx.x;
    int wave = t >> 6;
    int lane = t & 63;
    int gw   = blockIdx.x * 4 + wave;            // global wave 0..1023

    // ---------------- Phase A: prep ----------------
    // 4 atoms per wave: argmax(atom_to_token row) + glycan mask.
    #pragma unroll
    for (int q = 0; q < 4; ++q) {
        int atom = gw * 4 + q;                   // 0..4095
        const float* row = a2t + (size_t)atom * NTOK + lane * 4;
        float4 v = *(const float4*)row;
        float mv = v.x; int mi = lane * 4;
        if (v.y > mv) { mv = v.y; mi = lane * 4 + 1; }
        if (v.z > mv) { mv = v.z; mi = lane * 4 + 2; }
        if (v.w > mv) { mv = v.w; mi = lane * 4 + 3; }
        #pragma unroll
        for (int off = 32; off > 0; off >>= 1) {
            float ov = __shfl_down(mv, off);
            int   oi = __shfl_down(mi, off);
            if (ov > mv || (ov == mv && oi < mi)) { mv = ov; mi = oi; }
        }
        if (lane == 0) {
            tok[atom] = mi;
            g[atom]   = (mono[atom] != -1) ? 1 : 0;
        }
    }
    {   // 1 bond row per wave -> bit adjacency
        const float* p = bonds + (size_t)gw * NTOK;
        u64 w0 = __ballot(p[lane]       > 0.0f);
        u64 w1 = __ballot(p[lane + 64]  > 0.0f);
        u64 w2 = __ballot(p[lane + 128] > 0.0f);
        u64 w3 = __ballot(p[lane + 192] > 0.0f);
        if (lane == 0) {
            u64* d = adjw + (size_t)gw * 4;
            d[0] = w0; d[1] = w1; d[2] = w2; d[3] = w3;
        }
    }

    flag_barrier((unsigned*)(ws + OFF_F1), (unsigned*)(ws + OFF_REL1));

    // ---------------- Phase B: BFS (blocks 0..15) ----------------
    if (blockIdx.x < 16) {
        int b     = blockIdx.x >> 2;
        int chunk = blockIdx.x & 3;

        if (t < 8) usable32[t] = 0;
        {   // init dist chunk to 0xFFFF
            u16x8 ff = {0xFFFF,0xFFFF,0xFFFF,0xFFFF,0xFFFF,0xFFFF,0xFFFF,0xFFFF};
            u16x8* dp = (u16x8*)dist;
            #pragma unroll
            for (int k = 0; k < 8; ++k) dp[t + k * 256] = ff;
        }
        __syncthreads();
        #pragma unroll
        for (int q = 0; q < 4; ++q) {
            int a = b * NATOM + t + q * 256;
            if (g[a]) {
                int tt = tok[a];
                atomicOr(&usable32[tt >> 5], 1u << (tt & 31));
            }
        }
        __syncthreads();
        u64 um0 = ((u64)usable32[1] << 32) | usable32[0];
        u64 um1 = ((u64)usable32[3] << 32) | usable32[2];
        u64 um2 = ((u64)usable32[5] << 32) | usable32[4];
        u64 um3 = ((u64)usable32[7] << 32) | usable32[6];
        {   // masked adjacency row t (+ L[t] from chunk-0 blocks)
            const u64* arow = adjw + (size_t)(b * NTOK + t) * 4;
            u64 a0 = arow[0], a1 = arow[1], a2 = arow[2], a3 = arow[3];
            int w = t >> 6;
            u64 bt = 1ull << (t & 63);
            bool ut = (((w == 0) ? um0 : (w == 1) ? um1 : (w == 2) ? um2 : um3) >> (t & 63)) & 1;
            u64 m0 = ut ? (a0 & um0) : 0ull;
            u64 m1 = ut ? (a1 & um1) : 0ull;
            u64 m2 = ut ? (a2 & um2) : 0ull;
            u64 m3 = ut ? (a3 & um3) : 0ull;
            adjm[t * 4 + 0] = m0; adjm[t * 4 + 1] = m1;
            adjm[t * 4 + 2] = m2; adjm[t * 4 + 3] = m3;
            if (chunk == 0) {
                u64 selfbit = (((w == 0) ? a0 : (w == 1) ? a1 : (w == 2) ? a2 : a3) >> (t & 63)) & 1;
                u64 e0 = m0, e1 = m1, e2 = m2, e3 = m3;
                if (w == 0) e0 &= ~bt; else if (w == 1) e1 &= ~bt;
                else if (w == 2) e2 &= ~bt; else e3 &= ~bt;
                bool nb = (e0 | e1 | e2 | e3) != 0ull;
                Lws[b * NTOK + t] = selfbit ? 1 : (nb ? 2 : 0x7FFF);
            }
        }
        __syncthreads();
        {   // BFS: source per 4-lane group, lane w owns word w
            int sl = t >> 2;
            int w  = t & 3;
            int s  = chunk * 64 + sl;
            u64 r = ((s >> 6) == w) ? (1ull << (s & 63)) : 0ull;
            u64 f = r;
            unsigned short* drow = dist + sl * 256;
            const ulonglong2* adj2 = (const ulonglong2*)adjm;
            for (int level = 1; level < 256; ++level) {
                u64 p0 = 0, p1 = 0, p2 = 0, p3 = 0;
                u64 f_ = f;
                while (f_) {
                    int v = (w << 6) + __builtin_ctzll(f_);
                    f_ &= f_ - 1;
                    ulonglong2 q01 = adj2[v * 2];
                    ulonglong2 q23 = adj2[v * 2 + 1];
                    p0 |= q01.x; p1 |= q01.y; p2 |= q23.x; p3 |= q23.y;
                }
                p0 |= __shfl_xor(p0, 1); p0 |= __shfl_xor(p0, 2);
                p1 |= __shfl_xor(p1, 1); p1 |= __shfl_xor(p1, 2);
                p2 |= __shfl_xor(p2, 1); p2 |= __shfl_xor(p2, 2);
                p3 |= __shfl_xor(p3, 1); p3 |= __shfl_xor(p3, 2);
                u64 full = (w == 0) ? p0 : (w == 1) ? p1 : (w == 2) ? p2 : p3;
                u64 nw = full & ~r;
                int flag = (nw != 0ull);
                flag |= __shfl_xor(flag, 1);
                flag |= __shfl_xor(flag, 2);
                if (!flag) break;
                u64 n_ = nw;
                while (n_) {
                    int v = (w << 6) + __builtin_ctzll(n_);
                    n_ &= n_ - 1;
                    drow[v] = (unsigned short)level;
                }
                r |= nw;
                f = nw;
            }
        }
        __syncthreads();
        {   // flush chunk's 64 rows (32 KB) to ws
            const u16x8* src = (const u16x8*)dist;
            u16x8* dst = (u16x8*)(distg + ((size_t)b * NTOK + chunk * 64) * NTOK);
            #pragma unroll
            for (int k = 0; k < 8; ++k) dst[t + k * 256] = src[t + k * 256];
        }
    }

    flag_barrier((unsigned*)(ws + OFF_F2), (unsigned*)(ws + OFF_REL2));

    // ---------------- Phase C: expand (16 rows per block) ----------------
    for (int rr = 0; rr < 16; ++rr) {
        int R = blockIdx.x * 16 + rr;            // 0..4095
        int b = R >> 10;
        int i = R & 1023;
        int base = b * NATOM;
        int ti = tok[base + i];
        int gi = g[base + i];
        const unsigned short* Drow = distg + ((size_t)b * NTOK + ti) * NTOK;
        int Li = Lws[b * NTOK + ti];
        int Lval = (Li <= 255) ? Li : -1;
        int4 tj4 = ((const int4*)(tok + base))[t];
        uchar4 g4 = ((const uchar4*)(g + base))[t];
        int j0 = t * 4;
        int4 o;
        {
            int j = j0, tj = tj4.x, gj = g4.x;
            o.x = (i == j) ? 0 : ((!gi || !gj) ? -1 : ((tj == ti) ? Lval
                  : ((Drow[tj] <= 255) ? (int)Drow[tj] : -1)));
        }
        {
            int j = j0 + 1, tj = tj4.y, gj = g4.y;
            o.y = (i == j) ? 0 : ((!gi || !gj) ? -1 : ((tj == ti) ? Lval
                  : ((Drow[tj] <= 255) ? (int)Drow[tj] : -1)));
        }
        {
            int j = j0 + 2, tj = tj4.z, gj = g4.z;
            o.z = (i == j) ? 0 : ((!gi || !gj) ? -1 : ((tj == ti) ? Lval
                  : ((Drow[tj] <= 255) ? (int)Drow[tj] : -1)));
        }
        {
            int j = j0 + 3, tj = tj4.w, gj = g4.w;
            o.w = (i == j) ? 0 : ((!gi || !gj) ? -1 : ((tj == ti) ? Lval
                  : ((Drow[tj] <= 255) ? (int)Drow[tj] : -1)));
        }
        ((int4*)(out + ((size_t)(base + i)) * NATOM))[t] = o;
    }
}

extern "C" void kernel_launch(void* const* d_in, const int* in_sizes, int n_in,
                              void* d_out, int out_size, void* d_ws, size_t ws_size,
                              hipStream_t stream) {
    // inputs: [0] atom_pad_mask (unused), [1] atom_mono_idx int32,
    //         [2] token_bonds f32 (B,T,T,1), [3] atom_to_token f32 (B,N,T)
    const int*   mono  = (const int*)d_in[1];
    const float* bonds = (const float*)d_in[2];
    const float* a2t   = (const float*)d_in[3];

    k_fused<<<NBLK, 256, 0, stream>>>(mono, a2t, bonds, (char*)d_ws, (int*)d_out);
}

// Round 14
// 96.897 us; speedup vs baseline: 1.5105x; 1.5105x over previous
//
#include <hip/hip_runtime.h>
#include <stdint.h>

#define BATCH 4
#define NATOM 1024
#define NTOK  256
#define NBLK  256

typedef unsigned short u16x8 __attribute__((ext_vector_type(8)));
typedef unsigned long long u64;

// ---------------- ws layout (bytes) ----------------
// adj:   [0, 32768)         u64[1024][4]     raw token adjacency bits
// dist:  [32768, 557056)    u16[4][256][256] token APSP (0xFFFF unreachable)
// tok:   [557056, 573440)   int32[4096]
// g:     [573440, 577536)   u8[4096]
// L:     [577536, 579584)   u16[1024]
// f1:    [579584, 580608)   u32[256] barrier-1 flags   (poison 0xAA.. != 1)
// rel1:  [580608, 580612)   u32      barrier-1 release
// f2:    [580672, 581696)   u32[256] barrier-2 flags
// rel2:  [581696, 581700)   u32      barrier-2 release
#define OFF_ADJ  0
#define OFF_DIST 32768
#define OFF_TOK  557056
#define OFF_G    573440
#define OFF_L    577536
#define OFF_F1   579584
#define OFF_REL1 580608
#define OFF_F2   580672
#define OFF_REL2 581696

// Grid-wide barrier, poison-immune (write 1, test ==1; 0xAA.. poison != 1).
// R13 lesson: POLLING WITH atomicAdd(p,0) RMWs serializes at the memory-side
// atomic unit (~30us per barrier with 255 pollers). v2 polls with RELAXED
// agent-scope LOADS (global_load sc1 -- concurrent same-line reads don't
// serialize), arrives with RELEASE stores, and issues ONE acquire per waiter
// after the loop (release->acquire transitivity through the coordinator
// publishes every block's prior writes). Co-residency: 256 blocks on 256 CUs.
__device__ __forceinline__ void flag_barrier(unsigned* flags, unsigned* release) {
    __syncthreads();
    int t = threadIdx.x;
    if (blockIdx.x == 0) {
        if (t > 0 && t < NBLK) {
            while (__hip_atomic_load(&flags[t], __ATOMIC_RELAXED,
                                     __HIP_MEMORY_SCOPE_AGENT) != 1u)
                __builtin_amdgcn_s_sleep(8);
            (void)__hip_atomic_load(&flags[t], __ATOMIC_ACQUIRE,
                                    __HIP_MEMORY_SCOPE_AGENT);
        }
        __syncthreads();
        if (t == 0)
            __hip_atomic_store(release, 1u, __ATOMIC_RELEASE,
                               __HIP_MEMORY_SCOPE_AGENT);
    } else {
        if (t == 0) {
            __hip_atomic_store(&flags[blockIdx.x], 1u, __ATOMIC_RELEASE,
                               __HIP_MEMORY_SCOPE_AGENT);
            while (__hip_atomic_load(release, __ATOMIC_RELAXED,
                                     __HIP_MEMORY_SCOPE_AGENT) != 1u)
                __builtin_amdgcn_s_sleep(32);
            (void)__hip_atomic_load(release, __ATOMIC_ACQUIRE,
                                    __HIP_MEMORY_SCOPE_AGENT);
        }
        __syncthreads();
    }
}

__global__ __launch_bounds__(256) void k_fused(const int* __restrict__ mono,
                                               const float* __restrict__ a2t,
                                               const float* __restrict__ bonds,
                                               char* __restrict__ ws,
                                               int* __restrict__ out) {
    u64* adjw            = (u64*)(ws + OFF_ADJ);
    unsigned short* distg = (unsigned short*)(ws + OFF_DIST);
    int* tok             = (int*)(ws + OFF_TOK);
    unsigned char* g     = (unsigned char*)(ws + OFF_G);
    unsigned short* Lws  = (unsigned short*)(ws + OFF_L);

    __shared__ u64 adjm[NTOK * 4];               // 8 KB   (phase B)
    __shared__ unsigned usable32[8];
    __shared__ unsigned short dist[64 * NTOK];   // 32 KB  (phase B)

    int t    = threadIdx.x;
    int wave = t >> 6;
    int lane = t & 63;
    int gw   = blockIdx.x * 4 + wave;            // global wave 0..1023

    // ---------------- Phase A: prep ----------------
    // 4 atoms per wave: argmax(atom_to_token row) + glycan mask.
    #pragma unroll
    for (int q = 0; q < 4; ++q) {
        int atom = gw * 4 + q;                   // 0..4095
        const float* row = a2t + (size_t)atom * NTOK + lane * 4;
        float4 v = *(const float4*)row;
        float mv = v.x; int mi = lane * 4;
        if (v.y > mv) { mv = v.y; mi = lane * 4 + 1; }
        if (v.z > mv) { mv = v.z; mi = lane * 4 + 2; }
        if (v.w > mv) { mv = v.w; mi = lane * 4 + 3; }
        #pragma unroll
        for (int off = 32; off > 0; off >>= 1) {
            float ov = __shfl_down(mv, off);
            int   oi = __shfl_down(mi, off);
            if (ov > mv || (ov == mv && oi < mi)) { mv = ov; mi = oi; }
        }
        if (lane == 0) {
            tok[atom] = mi;
            g[atom]   = (mono[atom] != -1) ? 1 : 0;
        }
    }
    {   // 1 bond row per wave -> bit adjacency
        const float* p = bonds + (size_t)gw * NTOK;
        u64 w0 = __ballot(p[lane]       > 0.0f);
        u64 w1 = __ballot(p[lane + 64]  > 0.0f);
        u64 w2 = __ballot(p[lane + 128] > 0.0f);
        u64 w3 = __ballot(p[lane + 192] > 0.0f);
        if (lane == 0) {
            u64* d = adjw + (size_t)gw * 4;
            d[0] = w0; d[1] = w1; d[2] = w2; d[3] = w3;
        }
    }

    flag_barrier((unsigned*)(ws + OFF_F1), (unsigned*)(ws + OFF_REL1));

    // ---------------- Phase B: BFS (blocks 0..15) ----------------
    if (blockIdx.x < 16) {
        int b     = blockIdx.x >> 2;
        int chunk = blockIdx.x & 3;

        if (t < 8) usable32[t] = 0;
        {   // init dist chunk to 0xFFFF
            u16x8 ff = {0xFFFF,0xFFFF,0xFFFF,0xFFFF,0xFFFF,0xFFFF,0xFFFF,0xFFFF};
            u16x8* dp = (u16x8*)dist;
            #pragma unroll
            for (int k = 0; k < 8; ++k) dp[t + k * 256] = ff;
        }
        __syncthreads();
        #pragma unroll
        for (int q = 0; q < 4; ++q) {
            int a = b * NATOM + t + q * 256;
            if (g[a]) {
                int tt = tok[a];
                atomicOr(&usable32[tt >> 5], 1u << (tt & 31));
            }
        }
        __syncthreads();
        u64 um0 = ((u64)usable32[1] << 32) | usable32[0];
        u64 um1 = ((u64)usable32[3] << 32) | usable32[2];
        u64 um2 = ((u64)usable32[5] << 32) | usable32[4];
        u64 um3 = ((u64)usable32[7] << 32) | usable32[6];
        {   // masked adjacency row t (+ L[t] from chunk-0 blocks)
            const u64* arow = adjw + (size_t)(b * NTOK + t) * 4;
            u64 a0 = arow[0], a1 = arow[1], a2 = arow[2], a3 = arow[3];
            int w = t >> 6;
            u64 bt = 1ull << (t & 63);
            bool ut = (((w == 0) ? um0 : (w == 1) ? um1 : (w == 2) ? um2 : um3) >> (t & 63)) & 1;
            u64 m0 = ut ? (a0 & um0) : 0ull;
            u64 m1 = ut ? (a1 & um1) : 0ull;
            u64 m2 = ut ? (a2 & um2) : 0ull;
            u64 m3 = ut ? (a3 & um3) : 0ull;
            adjm[t * 4 + 0] = m0; adjm[t * 4 + 1] = m1;
            adjm[t * 4 + 2] = m2; adjm[t * 4 + 3] = m3;
            if (chunk == 0) {
                u64 selfbit = (((w == 0) ? a0 : (w == 1) ? a1 : (w == 2) ? a2 : a3) >> (t & 63)) & 1;
                u64 e0 = m0, e1 = m1, e2 = m2, e3 = m3;
                if (w == 0) e0 &= ~bt; else if (w == 1) e1 &= ~bt;
                else if (w == 2) e2 &= ~bt; else e3 &= ~bt;
                bool nb = (e0 | e1 | e2 | e3) != 0ull;
                Lws[b * NTOK + t] = selfbit ? 1 : (nb ? 2 : 0x7FFF);
            }
        }
        __syncthreads();
        {   // BFS: source per 4-lane group, lane w owns word w
            int sl = t >> 2;
            int w  = t & 3;
            int s  = chunk * 64 + sl;
            u64 r = ((s >> 6) == w) ? (1ull << (s & 63)) : 0ull;
            u64 f = r;
            unsigned short* drow = dist + sl * 256;
            const ulonglong2* adj2 = (const ulonglong2*)adjm;
            for (int level = 1; level < 256; ++level) {
                u64 p0 = 0, p1 = 0, p2 = 0, p3 = 0;
                u64 f_ = f;
                while (f_) {
                    int v = (w << 6) + __builtin_ctzll(f_);
                    f_ &= f_ - 1;
                    ulonglong2 q01 = adj2[v * 2];
                    ulonglong2 q23 = adj2[v * 2 + 1];
                    p0 |= q01.x; p1 |= q01.y; p2 |= q23.x; p3 |= q23.y;
                }
                p0 |= __shfl_xor(p0, 1); p0 |= __shfl_xor(p0, 2);
                p1 |= __shfl_xor(p1, 1); p1 |= __shfl_xor(p1, 2);
                p2 |= __shfl_xor(p2, 1); p2 |= __shfl_xor(p2, 2);
                p3 |= __shfl_xor(p3, 1); p3 |= __shfl_xor(p3, 2);
                u64 full = (w == 0) ? p0 : (w == 1) ? p1 : (w == 2) ? p2 : p3;
                u64 nw = full & ~r;
                int flag = (nw != 0ull);
                flag |= __shfl_xor(flag, 1);
                flag |= __shfl_xor(flag, 2);
                if (!flag) break;
                u64 n_ = nw;
                while (n_) {
                    int v = (w << 6) + __builtin_ctzll(n_);
                    n_ &= n_ - 1;
                    drow[v] = (unsigned short)level;
                }
                r |= nw;
                f = nw;
            }
        }
        __syncthreads();
        {   // flush chunk's 64 rows (32 KB) to ws
            const u16x8* src = (const u16x8*)dist;
            u16x8* dst = (u16x8*)(distg + ((size_t)b * NTOK + chunk * 64) * NTOK);
            #pragma unroll
            for (int k = 0; k < 8; ++k) dst[t + k * 256] = src[t + k * 256];
        }
    }

    flag_barrier((unsigned*)(ws + OFF_F2), (unsigned*)(ws + OFF_REL2));

    // ---------------- Phase C: expand (16 rows per block) ----------------
    for (int rr = 0; rr < 16; ++rr) {
        int R = blockIdx.x * 16 + rr;            // 0..4095
        int b = R >> 10;
        int i = R & 1023;
        int base = b * NATOM;
        int ti = tok[base + i];
        int gi = g[base + i];
        const unsigned short* Drow = distg + ((size_t)b * NTOK + ti) * NTOK;
        int Li = Lws[b * NTOK + ti];
        int Lval = (Li <= 255) ? Li : -1;
        int4 tj4 = ((const int4*)(tok + base))[t];
        uchar4 g4 = ((const uchar4*)(g + base))[t];
        int j0 = t * 4;
        int4 o;
        {
            int j = j0, tj = tj4.x, gj = g4.x;
            o.x = (i == j) ? 0 : ((!gi || !gj) ? -1 : ((tj == ti) ? Lval
                  : ((Drow[tj] <= 255) ? (int)Drow[tj] : -1)));
        }
        {
            int j = j0 + 1, tj = tj4.y, gj = g4.y;
            o.y = (i == j) ? 0 : ((!gi || !gj) ? -1 : ((tj == ti) ? Lval
                  : ((Drow[tj] <= 255) ? (int)Drow[tj] : -1)));
        }
        {
            int j = j0 + 2, tj = tj4.z, gj = g4.z;
            o.z = (i == j) ? 0 : ((!gi || !gj) ? -1 : ((tj == ti) ? Lval
                  : ((Drow[tj] <= 255) ? (int)Drow[tj] : -1)));
        }
        {
            int j = j0 + 3, tj = tj4.w, gj = g4.w;
            o.w = (i == j) ? 0 : ((!gi || !gj) ? -1 : ((tj == ti) ? Lval
                  : ((Drow[tj] <= 255) ? (int)Drow[tj] : -1)));
        }
        ((int4*)(out + ((size_t)(base + i)) * NATOM))[t] = o;
    }
}

extern "C" void kernel_launch(void* const* d_in, const int* in_sizes, int n_in,
                              void* d_out, int out_size, void* d_ws, size_t ws_size,
                              hipStream_t stream) {
    // inputs: [0] atom_pad_mask (unused), [1] atom_mono_idx int32,
    //         [2] token_bonds f32 (B,T,T,1), [3] atom_to_token f32 (B,N,T)
    const int*   mono  = (const int*)d_in[1];
    const float* bonds = (const float*)d_in[2];
    const float* a2t   = (const float*)d_in[3];

    k_fused<<<NBLK, 256, 0, stream>>>(mono, a2t, bonds, (char*)d_ws, (int*)d_out);
}

// Round 15
// 93.226 us; speedup vs baseline: 1.5699x; 1.0394x over previous
//
#include <hip/hip_runtime.h>
#include <stdint.h>

#define BATCH 4
#define NATOM 1024
#define NTOK  256
#define NBLK  256

typedef unsigned short u16x8 __attribute__((ext_vector_type(8)));
typedef unsigned long long u64;

// ---------------- ws layout (bytes) ----------------
// adj:   [0, 32768)         u64[1024][4]     raw token adjacency bits
// dist:  [32768, 557056)    u16[4][256][256] token APSP (0xFFFF unreachable)
// tok:   [557056, 573440)   u32[4096]
// g:     [573440, 589824)   u32[4096]  (widened to u32: clean 4B atomics)
// L:     [589824, 593920)   u32[1024]
// f1:    [593920, 594944)   u32[256] barrier-1 flags (poison 0xAA.. != 1)
// rel1:  [594944, 594948)   u32
// f2:    [595008, 596032)   u32[256] barrier-2 flags
// rel2:  [596032, 596036)   u32
#define OFF_ADJ  0
#define OFF_DIST 32768
#define OFF_TOK  557056
#define OFF_G    573440
#define OFF_L    589824
#define OFF_F1   593920
#define OFF_REL1 594944
#define OFF_F2   595008
#define OFF_REL2 596032

// v3 coherence scheme (R13/R14 lessons):
//  - R13: polling with atomicAdd(p,0) RMWs serializes at the atomic unit (~60us).
//  - R14: release/acquire fences at agent scope emit per-block L2 writeback/
//    invalidate ops (per-XCD L2s are non-coherent) -> ~25-35us residue.
//  - v3: ALL cross-phase data moves via RELAXED agent-scope atomic load/store
//    (write-through past L2, reads bypass L2). Barrier = s_waitcnt vmcnt(0)
//    per wave + __syncthreads + relaxed flag store; polls are relaxed loads.
//    Zero cache-maintenance instructions anywhere.
__device__ __forceinline__ unsigned ld_ag(const unsigned* p) {
    return __hip_atomic_load((unsigned*)p, __ATOMIC_RELAXED, __HIP_MEMORY_SCOPE_AGENT);
}
__device__ __forceinline__ u64 ld_ag64(const u64* p) {
    return __hip_atomic_load((u64*)p, __ATOMIC_RELAXED, __HIP_MEMORY_SCOPE_AGENT);
}
__device__ __forceinline__ void st_ag(unsigned* p, unsigned v) {
    __hip_atomic_store(p, v, __ATOMIC_RELAXED, __HIP_MEMORY_SCOPE_AGENT);
}
__device__ __forceinline__ void st_ag64(u64* p, u64 v) {
    __hip_atomic_store(p, v, __ATOMIC_RELAXED, __HIP_MEMORY_SCOPE_AGENT);
}

__device__ __forceinline__ void flag_barrier(unsigned* flags, unsigned* release) {
    // every wave drains its own write-through stores, then block-sync:
    // all of this block's data is globally visible before the arrival flag.
    asm volatile("s_waitcnt vmcnt(0)" ::: "memory");
    __syncthreads();
    int t = threadIdx.x;
    if (blockIdx.x == 0) {
        if (t > 0 && t < NBLK) {
            while (ld_ag(&flags[t]) != 1u) __builtin_amdgcn_s_sleep(8);
        }
        __syncthreads();
        if (t == 0) st_ag(release, 1u);
    } else {
        if (t == 0) {
            st_ag(&flags[blockIdx.x], 1u);
            while (ld_ag(release) != 1u) __builtin_amdgcn_s_sleep(16);
        }
        __syncthreads();
    }
    asm volatile("" ::: "memory");   // keep data loads after the poll
}

__global__ __launch_bounds__(256) void k_fused(const int* __restrict__ mono,
                                               const float* __restrict__ a2t,
                                               const float* __restrict__ bonds,
                                               char* __restrict__ ws,
                                               int* __restrict__ out) {
    u64* adjw      = (u64*)(ws + OFF_ADJ);
    unsigned short* distg = (unsigned short*)(ws + OFF_DIST);
    unsigned* toku = (unsigned*)(ws + OFF_TOK);
    unsigned* gu   = (unsigned*)(ws + OFF_G);
    unsigned* Lu   = (unsigned*)(ws + OFF_L);

    __shared__ u64 adjm[NTOK * 4];               // 8 KB   (phase B)
    __shared__ unsigned usable32[8];
    __shared__ unsigned short dist[64 * NTOK];   // 32 KB  (phase B)

    int t    = threadIdx.x;
    int wave = t >> 6;
    int lane = t & 63;
    int gw   = blockIdx.x * 4 + wave;            // global wave 0..1023

    // ---------------- Phase A: prep ----------------
    #pragma unroll
    for (int q = 0; q < 4; ++q) {
        int atom = gw * 4 + q;                   // 0..4095
        const float* row = a2t + (size_t)atom * NTOK + lane * 4;
        float4 v = *(const float4*)row;
        float mv = v.x; int mi = lane * 4;
        if (v.y > mv) { mv = v.y; mi = lane * 4 + 1; }
        if (v.z > mv) { mv = v.z; mi = lane * 4 + 2; }
        if (v.w > mv) { mv = v.w; mi = lane * 4 + 3; }
        #pragma unroll
        for (int off = 32; off > 0; off >>= 1) {
            float ov = __shfl_down(mv, off);
            int   oi = __shfl_down(mi, off);
            if (ov > mv || (ov == mv && oi < mi)) { mv = ov; mi = oi; }
        }
        if (lane == 0) {
            st_ag(&toku[atom], (unsigned)mi);
            st_ag(&gu[atom], (mono[atom] != -1) ? 1u : 0u);
        }
    }
    {   // 1 bond row per wave -> bit adjacency
        const float* p = bonds + (size_t)gw * NTOK;
        u64 w0 = __ballot(p[lane]       > 0.0f);
        u64 w1 = __ballot(p[lane + 64]  > 0.0f);
        u64 w2 = __ballot(p[lane + 128] > 0.0f);
        u64 w3 = __ballot(p[lane + 192] > 0.0f);
        if (lane == 0) {
            u64* d = adjw + (size_t)gw * 4;
            st_ag64(&d[0], w0); st_ag64(&d[1], w1);
            st_ag64(&d[2], w2); st_ag64(&d[3], w3);
        }
    }

    flag_barrier((unsigned*)(ws + OFF_F1), (unsigned*)(ws + OFF_REL1));

    // ---------------- Phase B: BFS (blocks 0..15) ----------------
    if (blockIdx.x < 16) {
        int b     = blockIdx.x >> 2;
        int chunk = blockIdx.x & 3;

        if (t < 8) usable32[t] = 0;
        {   // init dist chunk to 0xFFFF
            u16x8 ff = {0xFFFF,0xFFFF,0xFFFF,0xFFFF,0xFFFF,0xFFFF,0xFFFF,0xFFFF};
            u16x8* dp = (u16x8*)dist;
            #pragma unroll
            for (int k = 0; k < 8; ++k) dp[t + k * 256] = ff;
        }
        __syncthreads();
        #pragma unroll
        for (int q = 0; q < 4; ++q) {
            int a = b * NATOM + t + q * 256;
            if (ld_ag(&gu[a])) {
                unsigned tt = ld_ag(&toku[a]);
                atomicOr(&usable32[tt >> 5], 1u << (tt & 31));
            }
        }
        __syncthreads();
        u64 um0 = ((u64)usable32[1] << 32) | usable32[0];
        u64 um1 = ((u64)usable32[3] << 32) | usable32[2];
        u64 um2 = ((u64)usable32[5] << 32) | usable32[4];
        u64 um3 = ((u64)usable32[7] << 32) | usable32[6];
        {   // masked adjacency row t (+ L[t] from chunk-0 blocks)
            const u64* arow = adjw + (size_t)(b * NTOK + t) * 4;
            u64 a0 = ld_ag64(&arow[0]), a1 = ld_ag64(&arow[1]);
            u64 a2 = ld_ag64(&arow[2]), a3 = ld_ag64(&arow[3]);
            int w = t >> 6;
            u64 bt = 1ull << (t & 63);
            bool ut = (((w == 0) ? um0 : (w == 1) ? um1 : (w == 2) ? um2 : um3) >> (t & 63)) & 1;
            u64 m0 = ut ? (a0 & um0) : 0ull;
            u64 m1 = ut ? (a1 & um1) : 0ull;
            u64 m2 = ut ? (a2 & um2) : 0ull;
            u64 m3 = ut ? (a3 & um3) : 0ull;
            adjm[t * 4 + 0] = m0; adjm[t * 4 + 1] = m1;
            adjm[t * 4 + 2] = m2; adjm[t * 4 + 3] = m3;
            if (chunk == 0) {
                u64 selfbit = (((w == 0) ? a0 : (w == 1) ? a1 : (w == 2) ? a2 : a3) >> (t & 63)) & 1;
                u64 e0 = m0, e1 = m1, e2 = m2, e3 = m3;
                if (w == 0) e0 &= ~bt; else if (w == 1) e1 &= ~bt;
                else if (w == 2) e2 &= ~bt; else e3 &= ~bt;
                bool nb = (e0 | e1 | e2 | e3) != 0ull;
                st_ag(&Lu[b * NTOK + t], selfbit ? 1u : (nb ? 2u : 0x7FFFu));
            }
        }
        __syncthreads();
        {   // BFS: source per 4-lane group, lane w owns word w
            int sl = t >> 2;
            int w  = t & 3;
            int s  = chunk * 64 + sl;
            u64 r = ((s >> 6) == w) ? (1ull << (s & 63)) : 0ull;
            u64 f = r;
            unsigned short* drow = dist + sl * 256;
            const ulonglong2* adj2 = (const ulonglong2*)adjm;
            for (int level = 1; level < 256; ++level) {
                u64 p0 = 0, p1 = 0, p2 = 0, p3 = 0;
                u64 f_ = f;
                while (f_) {
                    int v = (w << 6) + __builtin_ctzll(f_);
                    f_ &= f_ - 1;
                    ulonglong2 q01 = adj2[v * 2];
                    ulonglong2 q23 = adj2[v * 2 + 1];
                    p0 |= q01.x; p1 |= q01.y; p2 |= q23.x; p3 |= q23.y;
                }
                p0 |= __shfl_xor(p0, 1); p0 |= __shfl_xor(p0, 2);
                p1 |= __shfl_xor(p1, 1); p1 |= __shfl_xor(p1, 2);
                p2 |= __shfl_xor(p2, 1); p2 |= __shfl_xor(p2, 2);
                p3 |= __shfl_xor(p3, 1); p3 |= __shfl_xor(p3, 2);
                u64 full = (w == 0) ? p0 : (w == 1) ? p1 : (w == 2) ? p2 : p3;
                u64 nw = full & ~r;
                int flag = (nw != 0ull);
                flag |= __shfl_xor(flag, 1);
                flag |= __shfl_xor(flag, 2);
                if (!flag) break;
                u64 n_ = nw;
                while (n_) {
                    int v = (w << 6) + __builtin_ctzll(n_);
                    n_ &= n_ - 1;
                    drow[v] = (unsigned short)level;
                }
                r |= nw;
                f = nw;
            }
        }
        __syncthreads();
        {   // flush chunk's 64 rows (32 KB) via relaxed agent u32 stores
            const unsigned* src = (const unsigned*)dist;
            unsigned* dst = (unsigned*)(distg + ((size_t)b * NTOK + chunk * 64) * NTOK);
            #pragma unroll
            for (int k = 0; k < 32; ++k) st_ag(&dst[t + k * 256], src[t + k * 256]);
        }
    }

    flag_barrier((unsigned*)(ws + OFF_F2), (unsigned*)(ws + OFF_REL2));

    // ---------------- Phase C: expand (16 rows per block, same batch) ----------------
    {
        int b    = (blockIdx.x * 16) >> 10;      // constant per block (1024%16==0)
        int base = b * NATOM;
        // hoist per-block column data: tok/g for j = 4t..4t+3
        unsigned tj_[4], gj_[4];
        #pragma unroll
        for (int e = 0; e < 4; ++e) {
            tj_[e] = ld_ag(&toku[base + 4 * t + e]);
            gj_[e] = ld_ag(&gu[base + 4 * t + e]);
        }
        for (int rr = 0; rr < 16; ++rr) {
            int R = blockIdx.x * 16 + rr;        // 0..4095
            int i = R & 1023;
            unsigned ti = ld_ag(&toku[base + i]);
            unsigned gi = ld_ag(&gu[base + i]);
            const unsigned* drow32 = (const unsigned*)(distg + ((size_t)b * NTOK + ti) * NTOK);
            unsigned Li = ld_ag(&Lu[b * NTOK + ti]);
            int Lval = (Li <= 255u) ? (int)Li : -1;
            int j0 = t * 4;
            int4 o;
            #pragma unroll
            for (int e = 0; e < 4; ++e) {
                int j = j0 + e;
                unsigned tj = tj_[e], gj = gj_[e];
                int oe;
                if (i == j) oe = 0;
                else if (!gi || !gj) oe = -1;
                else if (tj == ti) oe = Lval;
                else {
                    unsigned wv = ld_ag(&drow32[tj >> 1]);
                    unsigned dv = (tj & 1) ? (wv >> 16) : (wv & 0xFFFFu);
                    oe = (dv <= 255u) ? (int)dv : -1;
                }
                ((int*)&o)[e] = oe;
            }
            ((int4*)(out + ((size_t)(base + i)) * NATOM))[t] = o;  // plain store:
            // host reads after kernel end (implicit device release).
        }
    }
}

extern "C" void kernel_launch(void* const* d_in, const int* in_sizes, int n_in,
                              void* d_out, int out_size, void* d_ws, size_t ws_size,
                              hipStream_t stream) {
    // inputs: [0] atom_pad_mask (unused), [1] atom_mono_idx int32,
    //         [2] token_bonds f32 (B,T,T,1), [3] atom_to_token f32 (B,N,T)
    const int*   mono  = (const int*)d_in[1];
    const float* bonds = (const float*)d_in[2];
    const float* a2t   = (const float*)d_in[3];

    k_fused<<<NBLK, 256, 0, stream>>>(mono, a2t, bonds, (char*)d_ws, (int*)d_out);
}